// Round 6
// baseline (271.500 us; speedup 1.0000x reference)
//
#include <hip/hip_runtime.h>
#include <hip/hip_bf16.h>

#define BB 128
#define NN 2048
#define DD 128
#define HH 8

// ws float offsets (no zero-init required anywhere)
#define GSP_OFF  0          // [B][8][128] k1 partial sums = 131072
#define WQE_OFF  131072     // [B][H*128]  = 131072
#define SB_OFF   262144     // [B][H]      = 1024
#define ESP_OFF  263168     // [B][8][H]   k3 partial esums = 8192
#define E_OFF    271360     // [B][N][H]   = 2097152

// ---------- K1: gsp[b][cx][d] = sum over 256 rows of x[b][n][d] ----------
__launch_bounds__(256)
__global__ void k1_gsum(const float* __restrict__ x, float* __restrict__ gsp) {
    int b = blockIdx.y, cx = blockIdx.x, t = threadIdx.x;
    int c4 = t & 31, rg = t >> 5;                       // 32 float4-cols x 8 row-groups
    const float4* x4 = (const float4*)(x + ((size_t)b * NN + cx * 256) * DD);
    float4 acc = make_float4(0.f, 0.f, 0.f, 0.f);
    #pragma unroll 8
    for (int i = 0; i < 32; ++i) {
        float4 v = x4[(size_t)(rg + 8 * i) * 32 + c4];
        acc.x += v.x; acc.y += v.y; acc.z += v.z; acc.w += v.w;
    }
    acc.x += __shfl_xor(acc.x, 32, 64);
    acc.y += __shfl_xor(acc.y, 32, 64);
    acc.z += __shfl_xor(acc.z, 32, 64);
    acc.w += __shfl_xor(acc.w, 32, 64);
    __shared__ float xsum[4][32][4];
    int w = t >> 6, lane = t & 63;
    if (lane < 32) {
        xsum[w][lane][0] = acc.x; xsum[w][lane][1] = acc.y;
        xsum[w][lane][2] = acc.z; xsum[w][lane][3] = acc.w;
    }
    __syncthreads();
    if (t < 32) {
        float4 s;
        s.x = xsum[0][t][0] + xsum[1][t][0] + xsum[2][t][0] + xsum[3][t][0];
        s.y = xsum[0][t][1] + xsum[1][t][1] + xsum[2][t][1] + xsum[3][t][1];
        s.z = xsum[0][t][2] + xsum[1][t][2] + xsum[2][t][2] + xsum[3][t][2];
        s.w = xsum[0][t][3] + xsum[1][t][3] + xsum[2][t][3] + xsum[3][t][3];
        ((float4*)(gsp + ((size_t)b * 8 + cx) * 128))[t] = s;
    }
}

// ---------- K2: batched (4 b / block), LDS-staged weight chain ----------
// ctx -> q_in = Wl*ctx+bl -> q = Wq*q_in+bq -> wqe = 0.25*Wk-fold(q), sb
__launch_bounds__(256)
__global__ void k2(const float* __restrict__ x,
                   const int* __restrict__ fn_p, const int* __restrict__ cn_p,
                   const float* __restrict__ Wl, const float* __restrict__ blv,
                   const float* __restrict__ Wq, const float* __restrict__ bqv,
                   const float* __restrict__ Wk, const float* __restrict__ bkv,
                   float* ws) {
    __shared__ float ctxL[4][384];
    __shared__ float wT[128 * 33];
    __shared__ float qinL[4][128];
    __shared__ float qvL[4][128];
    int b0 = blockIdx.x * 4, t = threadIdx.x;   // 32 blocks, 256 threads

    // int64 vs int32 index-layout hedge
    bool is64 = (fn_p[1] == 0 && fn_p[3] == 0 && fn_p[5] == 0 && fn_p[7] == 0 &&
                 cn_p[1] == 0 && cn_p[3] == 0 && cn_p[5] == 0 && cn_p[7] == 0);

    // ctx gather for 4 batches
    #pragma unroll
    for (int q = 0; q < 4; ++q) {
        int b = b0 + q;
        int fn = is64 ? fn_p[2 * b] : fn_p[b];
        int cn = is64 ? cn_p[2 * b] : cn_p[b];
        const float* gsp = ws + GSP_OFF + (size_t)b * 1024;
        if (t < 128) {
            float g = 0.f;
            #pragma unroll
            for (int i = 0; i < 8; ++i) g += gsp[i * 128 + t];
            ctxL[q][t]       = g * (1.0f / NN);
            ctxL[q][256 + t] = x[((size_t)b * NN + cn) * DD + t];
        } else {
            int u = t - 128;
            ctxL[q][128 + u] = x[((size_t)b * NN + fn) * DD + u];
        }
    }

    int m = t & 127, pair = t >> 7;     // thread owns (m, b-local 2*pair and 2*pair+1)
    int bA = 2 * pair, bC = 2 * pair + 1;

    // ---- stage 1: q_in[m] = bl[m] + sum_e Wl[m][e]*ctx[e], 12 LDS tiles of 32 e ----
    float acc0 = 0.f, acc1 = 0.f;
    for (int tile = 0; tile < 12; ++tile) {
        int e0 = tile * 32;
        __syncthreads();
        #pragma unroll
        for (int k = 0; k < 16; ++k) {
            int idx = t + k * 256, r = idx >> 5, c = idx & 31;
            wT[r * 33 + c] = Wl[(size_t)r * 384 + e0 + c];     // coalesced
        }
        __syncthreads();
        #pragma unroll 8
        for (int e = 0; e < 32; ++e) {
            float w = wT[m * 33 + e];                           // bank (m+e)%32, 2-way free
            acc0 = fmaf(w, ctxL[bA][e0 + e], acc0);
            acc1 = fmaf(w, ctxL[bC][e0 + e], acc1);
        }
    }
    {
        float bb = blv[m];
        qinL[bA][m] = acc0 + bb;
        qinL[bC][m] = acc1 + bb;
    }

    // ---- stage 2: q[m] = bq[m] + sum_c Wq[m][c]*q_in[c], 4 LDS tiles of 32 c ----
    acc0 = 0.f; acc1 = 0.f;
    for (int tile = 0; tile < 4; ++tile) {
        int c0 = tile * 32;
        __syncthreads();
        #pragma unroll
        for (int k = 0; k < 16; ++k) {
            int idx = t + k * 256, r = idx >> 5, c = idx & 31;
            wT[r * 33 + c] = Wq[(size_t)r * 128 + c0 + c];
        }
        __syncthreads();
        #pragma unroll 8
        for (int c = 0; c < 32; ++c) {
            float w = wT[m * 33 + c];
            acc0 = fmaf(w, qinL[bA][c0 + c], acc0);
            acc1 = fmaf(w, qinL[bC][c0 + c], acc1);
        }
    }
    {
        float bb = bqv[m];
        qvL[bA][m] = acc0 + bb;
        qvL[bC][m] = acc1 + bb;
    }
    __syncthreads();

    // ---- stage 3: wqe[b][h][d] = 0.25 * sum_j qv[b][h*16+j]*Wk[h*16+j][d] (coalesced global Wk) ----
    #pragma unroll
    for (int i4 = 0; i4 < 4; ++i4) {
        int i = t + i4 * 256, h = i >> 7, d = i & 127;
        float s0 = 0.f, s1 = 0.f, s2 = 0.f, s3 = 0.f;
        #pragma unroll
        for (int j = 0; j < 16; ++j) {
            float w = Wk[(size_t)(h * 16 + j) * 128 + d];
            s0 = fmaf(qvL[0][h * 16 + j], w, s0);
            s1 = fmaf(qvL[1][h * 16 + j], w, s1);
            s2 = fmaf(qvL[2][h * 16 + j], w, s2);
            s3 = fmaf(qvL[3][h * 16 + j], w, s3);
        }
        ws[WQE_OFF + (size_t)(b0 + 0) * 1024 + i] = 0.25f * s0;
        ws[WQE_OFF + (size_t)(b0 + 1) * 1024 + i] = 0.25f * s1;
        ws[WQE_OFF + (size_t)(b0 + 2) * 1024 + i] = 0.25f * s2;
        ws[WQE_OFF + (size_t)(b0 + 3) * 1024 + i] = 0.25f * s3;
    }
    if (t < 32) {
        int bl_ = t >> 3, h = t & 7;
        float s = 0.f;
        #pragma unroll
        for (int j = 0; j < 16; ++j) s = fmaf(qvL[bl_][h * 16 + j], bkv[h * 16 + j], s);
        (ws + SB_OFF)[(b0 + bl_) * HH + h] = 0.25f * s;
    }
}

// mask layout: 0 = byte (np.bool_), 1 = int32, 2 = int64
__device__ __forceinline__ int detect_mask_kind(const int* mw) {
    int big = 0, oddnz = 0;
    #pragma unroll 8
    for (int i = 0; i < 64; ++i) {
        unsigned w = (unsigned)mw[i];
        if (w > 1u) big = 1;
        if ((i & 1) && w != 0u) oddnz = 1;
    }
    return big ? 0 : (oddnz ? 1 : 2);
}
__device__ __forceinline__ int mask_at(const unsigned char* mb, const int* mw, int kind, size_t idx) {
    if (kind == 0) return mb[idx];
    if (kind == 1) return mw[idx];
    return mw[2 * idx];
}

// ---------- K3: e[b][n][h] = mask ? 0 : exp(x[b,n]·wqe[b,h] + sb[b,h]); esp partials ----------
__global__ void k3(const float* __restrict__ x, const void* __restrict__ mask,
                   const float* __restrict__ ws_ro,
                   float* __restrict__ wse, float* __restrict__ esp) {
    __shared__ float4 wq4[256];     // wqe[b]: [h][q] as float4
    __shared__ float sbL[8];
    __shared__ float ps[4][8];
    int b = blockIdx.y, cx = blockIdx.x, t = threadIdx.x;   // grid (8, B), 256 thr
    const float4* wqe4 = (const float4*)(ws_ro + WQE_OFF + (size_t)b * 1024);
    wq4[t] = wqe4[t];
    if (t < 8) sbL[t] = (ws_ro + SB_OFF)[b * HH + t];
    __syncthreads();

    const unsigned char* mb = (const unsigned char*)mask;
    const int* mw = (const int*)mask;
    int mkind = detect_mask_kind(mw);

    int n = cx * 256 + t;
    const float4* xr = (const float4*)(x + ((size_t)b * NN + n) * DD);

    float acc[HH];
    #pragma unroll
    for (int h = 0; h < HH; ++h) acc[h] = sbL[h];

    #pragma unroll 4
    for (int q = 0; q < 32; ++q) {
        float4 v = xr[q];
        #pragma unroll
        for (int h = 0; h < HH; ++h) {
            float4 w = wq4[h * 32 + q];
            acc[h] = fmaf(v.x, w.x, fmaf(v.y, w.y, fmaf(v.z, w.z, fmaf(v.w, w.w, acc[h]))));
        }
    }

    int msk = mask_at(mb, mw, mkind, (size_t)b * NN + n);
    float ev[HH];
    #pragma unroll
    for (int h = 0; h < HH; ++h) ev[h] = msk ? 0.f : __expf(acc[h]);

    float4 E0 = make_float4(ev[0], ev[1], ev[2], ev[3]);
    float4 E1 = make_float4(ev[4], ev[5], ev[6], ev[7]);
    float4* wp = (float4*)(wse + ((size_t)b * NN + n) * 8);
    wp[0] = E0; wp[1] = E1;

    int w = t >> 6, lane = t & 63;
    #pragma unroll
    for (int h = 0; h < HH; ++h) {
        float v = ev[h];
        #pragma unroll
        for (int off = 32; off >= 1; off >>= 1) v += __shfl_xor(v, off, 64);
        if (lane == 0) ps[w][h] = v;
    }
    __syncthreads();
    if (t < 8)
        esp[((size_t)b * 8 + cx) * 8 + t] = ps[0][t] + ps[1][t] + ps[2][t] + ps[3][t];
}

// ---------- K4: out[b][n] = sum_h e[b][n][h] * (0.125/esum[b][h]) ----------
__global__ void k4_out(const float* __restrict__ wse, const float* __restrict__ esp,
                       float* __restrict__ out) {
    __shared__ float rinv[8];
    int b = blockIdx.y, cx = blockIdx.x, t = threadIdx.x;
    if (t < 8) {
        float s = 0.f;
        #pragma unroll
        for (int i = 0; i < 8; ++i) s += esp[((size_t)b * 8 + i) * 8 + t];
        rinv[t] = 0.125f / s;
    }
    __syncthreads();
    int n = cx * 256 + t;
    const float4* ep = (const float4*)(wse + ((size_t)b * NN + n) * 8);
    float4 e0 = ep[0], e1 = ep[1];
    out[(size_t)b * NN + n] =
        e0.x * rinv[0] + e0.y * rinv[1] + e0.z * rinv[2] + e0.w * rinv[3] +
        e1.x * rinv[4] + e1.y * rinv[5] + e1.z * rinv[6] + e1.w * rinv[7];
}

extern "C" void kernel_launch(void* const* d_in, const int* in_sizes, int n_in,
                              void* d_out, int out_size, void* d_ws, size_t ws_size,
                              hipStream_t stream) {
    const float* x  = (const float*)d_in[0];
    const int* fn   = (const int*)d_in[1];
    const int* cn   = (const int*)d_in[2];
    const void* mk  = d_in[3];
    const float* Wl = (const float*)d_in[4];
    const float* bl = (const float*)d_in[5];
    const float* Wq = (const float*)d_in[6];
    const float* bq = (const float*)d_in[7];
    const float* Wk = (const float*)d_in[8];
    const float* bk = (const float*)d_in[9];
    float* ws  = (float*)d_ws;
    float* out = (float*)d_out;

    k1_gsum<<<dim3(8, BB), 256, 0, stream>>>(x, ws + GSP_OFF);
    k2<<<32, 256, 0, stream>>>(x, fn, cn, Wl, bl, Wq, bq, Wk, bk, ws);
    k3<<<dim3(8, BB), 256, 0, stream>>>(x, mk, ws, ws + E_OFF, ws + ESP_OFF);
    k4_out<<<dim3(8, BB), 256, 0, stream>>>(ws + E_OFF, ws + ESP_OFF, out);
}